// Round 8
// baseline (239.512 us; speedup 1.0000x reference)
//
#include <hip/hip_runtime.h>

#define H 8
#define NSEQ 4096
#define DIM 64
#define BATCH 8
#define AREV_LEN 4368   // 4096 lags + 272 zero pad (max read elem 4366). 2184 dwords.
#define AREV_DW (AREV_LEN/2)   // 2184
#define XPLEN 4144      // 16 front zeros (shifted-col reads) + 4096 + 32 tail pad.
#define HD (H*DIM)      // 512

typedef __attribute__((ext_vector_type(8))) short short8;
typedef __attribute__((ext_vector_type(4))) float float4v;
typedef __attribute__((ext_vector_type(4))) unsigned int uint4v;
typedef const __attribute__((address_space(1))) unsigned int* gas_u32p;
typedef __attribute__((address_space(3))) unsigned int* las_u32p;

template<int V> struct ic { static constexpr int value = V; };

__device__ inline unsigned short f32_to_bf16(float f) {
    unsigned int u = __float_as_uint(f);
    u += 0x7fffu + ((u >> 16) & 1u);   // RNE
    return (unsigned short)(u >> 16);
}

// ---- P1: arev[hd][i] = bf16( exp(clamp(log(gamma)*k + pos[k-1])) ) at k = 4095 - i ----
__global__ __launch_bounds__(256) void build_arev(
    const float* __restrict__ zero, const float* __restrict__ pos,
    const float* __restrict__ gamma, unsigned short* __restrict__ arev)
{
    __shared__ float lg[64];
    __shared__ unsigned short T[64][65];
    int h = blockIdx.y, kb = blockIdx.x;
    int tid = threadIdx.x;
    if (tid < 64) lg[tid] = logf(gamma[h*64 + tid]);
    __syncthreads();
    #pragma unroll
    for (int jj = 0; jj < 16; ++jj) {
        int e = tid + 256*jj;
        int kk = e >> 6, dd = e & 63;
        int k = kb*64 + kk;
        float v;
        if (k == 0) v = zero[h*64 + dd];
        else        v = lg[dd] * (float)k + pos[(h*4095 + (k-1))*64 + dd];
        v = fminf(30.f, fmaxf(-60.f, v));
        T[kk][dd] = f32_to_bf16(expf(v));
    }
    __syncthreads();
    int i0 = 4032 - kb*64;   // tile writes arev[hd][i0 .. i0+63], i = 4095 - k
    #pragma unroll
    for (int jj = 0; jj < 16; ++jj) {
        int e = tid + 256*jj;
        int dpr = e >> 6, ii = e & 63;
        arev[(size_t)(h*64 + dpr)*AREV_LEN + i0 + ii] = T[63 - ii][dpr];
    }
    unsigned short* pr = arev + (size_t)(h*64 + kb)*AREV_LEN + 4096;
    for (int i = tid; i < AREV_LEN - 4096; i += 256) pr[i] = 0;
}

// ---- P2: xp[hd][b][16 + s] = bf16(x[b][h][s][d]); rows front/tail zero-padded ----
__global__ __launch_bounds__(256) void build_xp(
    const float* __restrict__ x, unsigned short* __restrict__ xp)
{
    __shared__ unsigned short T[64][66];   // stride 66: dword-aligned, conflict-free cols
    int sb = blockIdx.x, h = blockIdx.y, b = blockIdx.z;
    int tid = threadIdx.x;
    const float4v* src4 =
        (const float4v*)(x + ((size_t)(b*H + h)*NSEQ + sb*64)*DIM);
    #pragma unroll
    for (int jj = 0; jj < 4; ++jj) {
        int e = tid + 256*jj;            // [0,1024)
        int ss = e >> 4, d4 = e & 15;
        float4v f = src4[ss*16 + d4];
        #pragma unroll
        for (int k = 0; k < 4; ++k) T[ss][4*d4 + k] = f32_to_bf16(f[k]);
    }
    __syncthreads();
    unsigned int* xp32 = (unsigned int*)xp;
    #pragma unroll
    for (int jj = 0; jj < 8; ++jj) {
        int e = tid + 256*jj;            // [0,2048)
        int dpr = e >> 5, c2 = e & 31;   // row d, dword col (2 s-elems)
        unsigned int lo = T[2*c2][dpr], hi = T[2*c2 + 1][dpr];
        size_t dwofs = (((size_t)(h*64 + dpr)*BATCH + b)*XPLEN + 16 + sb*64) >> 1;
        xp32[dwofs + c2] = lo | (hi << 16);
    }
    if (sb == 0) {
        for (int e = tid; e < 64*16; e += 256) {
            int dd = e >> 4, i = e & 15;
            xp[((size_t)(h*64 + dd)*BATCH + b)*XPLEN + i] = 0;
        }
    }
    if (sb == 63) {
        for (int e = tid; e < 64*32; e += 256) {
            int dd = e >> 5, i = e & 31;
            xp[((size_t)(h*64 + dd)*BATCH + b)*XPLEN + 16 + NSEQ + i] = 0;
        }
    }
}

// ---- GEMM: per (h,d): Out[t, 0:8] = sum_s a[t-s] * X[s, 0:8], causal ----
// One WG = one (h,d) + band pair {p,3-p}; every wave 136 k-steps (34 of 40
// 128-s windows active -- equal for all waves/pairs). OCCUPANCY is the design
// driver this round: unified VGPR+AGPR footprint ~100/wave (acc 32 + rg[8] 32
// + B4 16 + addr) with __launch_bounds__(256,4) -> 4 waves/SIMD, and LDS cut
// to 29.8KB (17.5 A + 3x4KB triple-buffered B) so all 4 blocks/CU co-reside
// in ONE round (R1-R7 ran at 2-3 waves/SIMD, unified-register-limited: every
// schedule variant hit the same ~127us latency wall).
// Triple-buffer safety: barrier bounds wave skew to 1 window; stage at window
// t writes buf (t+1)%3, concurrent readers touch t%3 and (t-1)%3 only.
__global__ __launch_bounds__(256, 4) void toeplitz_gemm(
    const unsigned short* __restrict__ arev,
    const unsigned short* __restrict__ xp,
    float* __restrict__ out)
{
    __shared__ unsigned int ldsA[2*AREV_DW];   // 17.5 KB: arev dwords + 1-elem shift
    __shared__ uint4v ldsB[3*256];             // 12 KB: triple-buffered 4KB B tiles

    // swizzle: 16 line-sharing consecutive-d WGs -> same XCD (id%8).
    int id = blockIdx.x;                 // [0, 1024)
    int q8 = id >> 7, rem = id & 127;
    int r  = rem >> 3, xx = rem & 7;
    int g  = q8*8 + xx;                  // [0, 64)
    int nlin = g*16 + r;                 // [0, 1024)
    int p  = nlin >> 9;                  // band pair: {p, 3-p}
    int h  = (nlin >> 6) & 7;
    int d  = nlin & 63;
    int hd = h*64 + d;

    int tid = threadIdx.x;
    const unsigned int* g32 = (const unsigned int*)(arev + (size_t)hd*AREV_LEN);
    int i0s = p << 9;                    // pair {1,2} never reads lag idx < 1024
    for (int i = i0s + tid; i < AREV_DW; i += 256) ldsA[i] = g32[i];
    for (int i = i0s + tid; i < AREV_DW - 1; i += 256)
        ldsA[AREV_DW + i] = (g32[i] >> 16) | (g32[i+1] << 16);  // elems 2i+1, 2i+2

    int w = tid >> 6, lane = tid & 63;
    int nb = lane & 15;        // A-frag row m and B-frag col n
    int q  = lane >> 4;        // k-quad
    int swz  = (nb >> 1) & 3;
    int bq16 = nb*4 + (q ^ swz);   // swizzled B-frag uint4 index within a 4KB tile

    // staging: wave w stages sub-chunk w (32 s x 16 rows = 1KB) of each window
    // via ONE global_load_lds w16; swizzle folded into the GLOBAL source.
    int rnb = lane >> 2, rq = lane & 3, rswz = (rnb >> 1) & 3;
    const unsigned short* xsrc =
        xp + ((size_t)hd*BATCH + (rnb & 7))*XPLEN + 16 - ((rnb >> 3) << 4)
           + 32*w + 8*(rq ^ rswz);

    int W1 = (p + 1) * 8;      // phase-1 windows; WT = 40 for both pairs
    const int WT = 40;

    auto stg = [&](int t) {
        int S = ((t < W1) ? t : t - W1) << 7;
        __builtin_amdgcn_global_load_lds(
            (gas_u32p)(const void*)(xsrc + S),
            (las_u32p)(void*)&ldsB[(t % 3)*256 + w*64], 16, 0, 0);
    };

    int tsh = (nb >> 3) << 4;
    float* obase = out + ((size_t)((nb & 7)*H + h)*NSEQ)*DIM + d;

    // persistent state -- all statically indexed, ~100 unified regs total
    float4v acc[8];            // 32
    short8  rg[8];             // 32: A-ring, slot (u-j)&7 at global k-step u
    int dwb = 0, s_end = 0, bW = 0;

    auto LFA = [&](int so) -> short8 {
        int dw = dwb + (so >> 1);    // so always even; parity folded into dwb
        union { short8 v; unsigned int u4[4]; } af;
        af.u4[0] = ldsA[dw];   af.u4[1] = ldsA[dw+1];
        af.u4[2] = ldsA[dw+2]; af.u4[3] = ldsA[dw+3];
        return af.v;
    };
    auto LFB = [&](int bb, int v) -> short8 {
        union { short8 vv; uint4v u4; } bf_;
        bf_.u4 = ldsB[bb + v*64 + bq16];   // single ds_read_b128, 16B-aligned
        return bf_.vv;
    };

    auto init_phase = [&](int b) {   // called only at ring phase M == 0
        bW = b;
        s_end = b + 240;             // multiple of 128 after +16 offset folds
        int B0 = 4095 - b - nb;
        int ofs = B0 + 8*q;
        dwb = ((ofs & 1) ? AREV_DW : 0) + (ofs >> 1);
        #pragma unroll
        for (int k = 0; k < 8; ++k) rg[(8 - k) & 7] = LFA(-32*k);
        #pragma unroll
        for (int j = 0; j < 8; ++j) acc[j] = (float4v){0.f,0.f,0.f,0.f};
    };
    auto store_acc = [&]() {
        #pragma unroll
        for (int j = 0; j < 8; ++j) {
            #pragma unroll
            for (int rr = 0; rr < 4; ++rr) {
                int t2 = bW - tsh + 32*j + 4*q + rr;
                obase[(size_t)t2*DIM] = acc[j][rr];
            }
        }
    };

    // prologue: ldsA visible; stage(0) in flight (awaited by window 0's vmcnt).
    stg(0);
    asm volatile("s_waitcnt lgkmcnt(0)" ::: "memory");
    __builtin_amdgcn_sched_barrier(0);
    __builtin_amdgcn_s_barrier();
    init_phase((p << 10) + 256*w + 16);

    auto window = [&](int t, auto mtag) {
        constexpr int M = decltype(mtag)::value;   // ring phase (4t)&7
        if (t + 1 < WT) stg(t + 1);
        // counted wait: stage(t) complete, stage(t+1) stays in flight.
        if (t < WT - 1) asm volatile("s_waitcnt vmcnt(1)" ::: "memory");
        else            asm volatile("s_waitcnt vmcnt(0)" ::: "memory");
        __builtin_amdgcn_sched_barrier(0);
        __builtin_amdgcn_s_barrier();

        if constexpr (M == 0) {      // W1 is a multiple of 2 -> switch at M==0
            if (t == W1) {
                store_acc();
                init_phase(((3 - p) << 10) + 256*(3 - w) + 16);
            }
        }

        int S = (((t < W1) ? t : t - W1)) << 7;
        if (S < s_end) {             // wave-uniform; idle waves still barrier
            int bb = (t % 3) * 256;
            short8 B4[4];
            #pragma unroll
            for (int v = 0; v < 4; ++v) B4[v] = LFB(bb, v);
            #pragma unroll
            for (int v = 0; v < 4; ++v) {
                #pragma unroll
                for (int j = 7; j >= 0; --j)
                    acc[j] = __builtin_amdgcn_mfma_f32_16x16x32_bf16(
                        rg[(M + v - j) & 7], B4[v], acc[j], 0, 0, 0);
                rg[(M + v + 1) & 7] = LFA(S + 32*(v + 1));  // ring feed, static slot
            }
        }
    };

    for (int tp = 0; tp < 20; ++tp) {   // window pairs: ring phase M = 0, 4
        window(2*tp,     ic<0>{});
        window(2*tp + 1, ic<4>{});
    }
    store_acc();
}

extern "C" void kernel_launch(void* const* d_in, const int* in_sizes, int n_in,
                              void* d_out, int out_size, void* d_ws, size_t ws_size,
                              hipStream_t stream) {
    const float* x     = (const float*)d_in[0];
    const float* zero  = (const float*)d_in[1];
    const float* pos   = (const float*)d_in[2];
    const float* gamma = (const float*)d_in[3];
    float* out = (float*)d_out;

    unsigned short* arev = (unsigned short*)d_ws;                 // 512*4368*2 = 4.47 MB
    unsigned short* xp   = arev + (size_t)HD*AREV_LEN;            // 512*8*4144*2 = 33.9 MB

    build_arev<<<dim3(64, 8), 256, 0, stream>>>(zero, pos, gamma, arev);
    build_xp<<<dim3(64, 8, 8), 256, 0, stream>>>(x, xp);
    toeplitz_gemm<<<dim3(1024), 256, 0, stream>>>(arev, xp, out);
}